// Round 7
// baseline (193.806 us; speedup 1.0000x reference)
//
#include <hip/hip_runtime.h>
#include <stdint.h>

#define DIMD 512
#define ROWS 65536

// ---- fused cooperative geometry ----
#define GRID  512
#define BLOCK 512               // 8 waves/block, 2 blocks/CU co-resident
#define WPB   8
#define RPW   16                // rows/wave: 8 named-reg + 4 LDS + 4 L3-reread
#define LDS_ROWS 4              // 32 rows/block * 2 KiB = 64 KiB LDS

// ---- fallback (proven R3) geometry ----
#define FB_BLOCKS 2048
#define FB_WPB    4
#define FB_RPW    8

typedef float vfloat4 __attribute__((ext_vector_type(4)));

// distance accumulate + wave-reduce + running min-key
__device__ __forceinline__ void dist_min(const float4 wa, const float4 wb,
                                         const float4 xa, const float4 xb,
                                         int row, unsigned long long& best)
{
    float s = 0.0f, t;
    t = wa.x - xa.x; s = fmaf(t, t, s);
    t = wa.y - xa.y; s = fmaf(t, t, s);
    t = wa.z - xa.z; s = fmaf(t, t, s);
    t = wa.w - xa.w; s = fmaf(t, t, s);
    t = wb.x - xb.x; s = fmaf(t, t, s);
    t = wb.y - xb.y; s = fmaf(t, t, s);
    t = wb.z - xb.z; s = fmaf(t, t, s);
    t = wb.w - xb.w; s = fmaf(t, t, s);
    #pragma unroll
    for (int off = 32; off > 0; off >>= 1)
        s += __shfl_xor(s, off, 64);
    const unsigned long long key =
        (((unsigned long long)__float_as_uint(s)) << 32) |
        (unsigned long long)(unsigned)row;
    best = (key < best) ? key : best;
}

// fused update + winner extraction for one row
__device__ __forceinline__ void update_row(const float4 wa, const float4 wb,
                                           const float4 xa, const float4 xb,
                                           int row, unsigned bmu,
                                           float bi, float bj,
                                           float alpha_op, float inv_s2,
                                           float* __restrict__ winner,
                                           float* __restrict__ new_weights,
                                           int lane)
{
    const float di = (float)(row >> 8) - bi;
    const float dj = (float)(row & 255) - bj;
    const float coef = alpha_op * __expf(-(di * di + dj * dj) * inv_s2);

    vfloat4 oa, ob;
    oa.x = fmaf(coef, xa.x - wa.x, wa.x);
    oa.y = fmaf(coef, xa.y - wa.y, wa.y);
    oa.z = fmaf(coef, xa.z - wa.z, wa.z);
    oa.w = fmaf(coef, xa.w - wa.w, wa.w);
    ob.x = fmaf(coef, xb.x - wb.x, wb.x);
    ob.y = fmaf(coef, xb.y - wb.y, wb.y);
    ob.z = fmaf(coef, xb.z - wb.z, wb.z);
    ob.w = fmaf(coef, xb.w - wb.w, wb.w);

    vfloat4* o4 = reinterpret_cast<vfloat4*>(new_weights + (size_t)row * DIMD);
    __builtin_nontemporal_store(oa, o4 + lane);
    __builtin_nontemporal_store(ob, o4 + lane + 64);

    if (row == (int)bmu) {
        float4* wn = reinterpret_cast<float4*>(winner);
        wn[lane]      = wa;   // OLD weights row
        wn[lane + 64] = wb;
    }
}

// ===========================================================================
// FUSED PATH (cooperative). Phase 1 streams each weight row once from HBM;
// rows 0-7 parked in NAMED register variables (no arrays -> nothing the
// compiler can demote to scratch), rows 8-11 in LDS, rows 12-15 re-read from
// L3 in phase 2. Hand-rolled grid barrier (-1-based, single 0xFF memset).
// ===========================================================================
__global__ __launch_bounds__(BLOCK, 4) void som_fused(
    const float* __restrict__ x,
    const float* __restrict__ w,
    const int* __restrict__ it_ptr,
    unsigned long long* __restrict__ slots,   // [GRID], 0xFF per call
    int* __restrict__ bar,                    // [2] = {cnt, flag}, 0xFF init
    float* __restrict__ out)
{
    __shared__ float lds[WPB * LDS_ROWS * DIMD];   // 64 KiB

    const int lane = threadIdx.x & 63;
    const int wave = threadIdx.x >> 6;
    const int row0 = (blockIdx.x * WPB + wave) * RPW;

    const float4* x4 = reinterpret_cast<const float4*>(x);
    const float4 xa = x4[lane];
    const float4 xb = x4[lane + 64];

    const float4* wb4 = reinterpret_cast<const float4*>(w);
    unsigned long long best = ~0ull;

    // ---- phase 1: rows 0-7 -> named registers ----
    float4 a0, b0, a1, b1, a2, b2, a3, b3, a4, b4, a5, b5, a6, b6, a7, b7;
    {
        const float4* p;
        p = wb4 + (size_t)(row0 + 0) * (DIMD / 4);
        a0 = p[lane]; b0 = p[lane + 64]; dist_min(a0, b0, xa, xb, row0 + 0, best);
        p = wb4 + (size_t)(row0 + 1) * (DIMD / 4);
        a1 = p[lane]; b1 = p[lane + 64]; dist_min(a1, b1, xa, xb, row0 + 1, best);
        p = wb4 + (size_t)(row0 + 2) * (DIMD / 4);
        a2 = p[lane]; b2 = p[lane + 64]; dist_min(a2, b2, xa, xb, row0 + 2, best);
        p = wb4 + (size_t)(row0 + 3) * (DIMD / 4);
        a3 = p[lane]; b3 = p[lane + 64]; dist_min(a3, b3, xa, xb, row0 + 3, best);
        p = wb4 + (size_t)(row0 + 4) * (DIMD / 4);
        a4 = p[lane]; b4 = p[lane + 64]; dist_min(a4, b4, xa, xb, row0 + 4, best);
        p = wb4 + (size_t)(row0 + 5) * (DIMD / 4);
        a5 = p[lane]; b5 = p[lane + 64]; dist_min(a5, b5, xa, xb, row0 + 5, best);
        p = wb4 + (size_t)(row0 + 6) * (DIMD / 4);
        a6 = p[lane]; b6 = p[lane + 64]; dist_min(a6, b6, xa, xb, row0 + 6, best);
        p = wb4 + (size_t)(row0 + 7) * (DIMD / 4);
        a7 = p[lane]; b7 = p[lane + 64]; dist_min(a7, b7, xa, xb, row0 + 7, best);
    }

    // ---- phase 1: rows 8-11 -> LDS ----
    #pragma unroll
    for (int r = 8; r < 8 + LDS_ROWS; ++r) {
        const float4* p = wb4 + (size_t)(row0 + r) * (DIMD / 4);
        const float4 wa = p[lane];
        const float4 wbv = p[lane + 64];
        float4* dst = reinterpret_cast<float4*>(
            lds + (wave * LDS_ROWS + (r - 8)) * DIMD);
        dst[lane]      = wa;
        dst[lane + 64] = wbv;
        dist_min(wa, wbv, xa, xb, row0 + r, best);
    }

    // ---- phase 1: rows 12-15 -> distance only (phase 2 re-reads from L3) ----
    #pragma unroll
    for (int r = 12; r < 16; ++r) {
        const float4* p = wb4 + (size_t)(row0 + r) * (DIMD / 4);
        dist_min(p[lane], p[lane + 64], xa, xb, row0 + r, best);
    }

    if (lane == 0) atomicMin(&slots[blockIdx.x], best);

    // ---- grid barrier: arrive (release) / spin (acquire), -1-based ----
    __syncthreads();
    if (threadIdx.x == 0) {
        __threadfence();
        const int old = __hip_atomic_fetch_add(&bar[0], 1, __ATOMIC_ACQ_REL,
                                               __HIP_MEMORY_SCOPE_AGENT);
        if (old == GRID - 2) {
            __hip_atomic_store(&bar[1], 1, __ATOMIC_RELEASE,
                               __HIP_MEMORY_SCOPE_AGENT);
        } else {
            while (__hip_atomic_load(&bar[1], __ATOMIC_ACQUIRE,
                                     __HIP_MEMORY_SCOPE_AGENT) == -1) {
                __builtin_amdgcn_s_sleep(2);
            }
        }
        __threadfence();
    }
    __syncthreads();

    // ---- every wave reduces the 512 per-block candidates ----
    unsigned long long g = ~0ull;
    #pragma unroll
    for (int k = 0; k < GRID / 64; ++k) {
        const unsigned long long v = slots[k * 64 + lane];
        g = (v < g) ? v : g;
    }
    #pragma unroll
    for (int off = 32; off > 0; off >>= 1) {
        const unsigned long long o = __shfl_xor(g, off, 64);
        g = (o < g) ? o : g;
    }

    const unsigned bmu = (unsigned)(g & 0xFFFFFFFFull);
    const float bi = (float)(bmu >> 8);
    const float bj = (float)(bmu & 255u);

    const double itd      = (double)(*it_ptr);
    const double lr       = 1.0 - itd / 1000.0;
    const float  alpha_op = (float)(0.3 * lr);
    const double sigma_op = 128.0 * lr;            // SIGMA = max(M,N)/2
    const float  inv_s2   = (float)(1.0 / (sigma_op * sigma_op));

    float* winner      = out;
    float* new_weights = out + DIMD;

    // ---- phase 2: named-register rows first (frees regs progressively) ----
    update_row(a0, b0, xa, xb, row0 + 0, bmu, bi, bj, alpha_op, inv_s2, winner, new_weights, lane);
    update_row(a1, b1, xa, xb, row0 + 1, bmu, bi, bj, alpha_op, inv_s2, winner, new_weights, lane);
    update_row(a2, b2, xa, xb, row0 + 2, bmu, bi, bj, alpha_op, inv_s2, winner, new_weights, lane);
    update_row(a3, b3, xa, xb, row0 + 3, bmu, bi, bj, alpha_op, inv_s2, winner, new_weights, lane);
    update_row(a4, b4, xa, xb, row0 + 4, bmu, bi, bj, alpha_op, inv_s2, winner, new_weights, lane);
    update_row(a5, b5, xa, xb, row0 + 5, bmu, bi, bj, alpha_op, inv_s2, winner, new_weights, lane);
    update_row(a6, b6, xa, xb, row0 + 6, bmu, bi, bj, alpha_op, inv_s2, winner, new_weights, lane);
    update_row(a7, b7, xa, xb, row0 + 7, bmu, bi, bj, alpha_op, inv_s2, winner, new_weights, lane);

    // ---- phase 2: LDS rows ----
    #pragma unroll
    for (int r = 8; r < 8 + LDS_ROWS; ++r) {
        const float4* src = reinterpret_cast<const float4*>(
            lds + (wave * LDS_ROWS + (r - 8)) * DIMD);
        update_row(src[lane], src[lane + 64], xa, xb, row0 + r, bmu,
                   bi, bj, alpha_op, inv_s2, winner, new_weights, lane);
    }

    // ---- phase 2: L3 re-read rows ----
    #pragma unroll
    for (int r = 12; r < 16; ++r) {
        const float4* p = wb4 + (size_t)(row0 + r) * (DIMD / 4);
        update_row(p[lane], p[lane + 64], xa, xb, row0 + r, bmu,
                   bi, bj, alpha_op, inv_s2, winner, new_weights, lane);
    }
}

// ===========================================================================
// FALLBACK PATH — byte-identical to the proven R3 two-kernel version.
// ===========================================================================
__global__ __launch_bounds__(256) void som_argmin_kernel(
    const float* __restrict__ x,
    const float* __restrict__ w,
    unsigned long long* __restrict__ slots)
{
    const int lane  = threadIdx.x & 63;
    const int wave  = threadIdx.x >> 6;
    const int gwave = blockIdx.x * FB_WPB + wave;
    const int row0  = gwave * FB_RPW;

    const float4* x4 = reinterpret_cast<const float4*>(x);
    const float4 xa = x4[lane];
    const float4 xb = x4[lane + 64];

    float d[FB_RPW];

    #pragma unroll
    for (int r = 0; r < FB_RPW; ++r) {
        const float4* w4 =
            reinterpret_cast<const float4*>(w + (size_t)(row0 + r) * DIMD);
        const float4 wa = w4[lane];
        const float4 wb = w4[lane + 64];

        float s = 0.0f, t;
        t = wa.x - xa.x; s = fmaf(t, t, s);
        t = wa.y - xa.y; s = fmaf(t, t, s);
        t = wa.z - xa.z; s = fmaf(t, t, s);
        t = wa.w - xa.w; s = fmaf(t, t, s);
        t = wb.x - xb.x; s = fmaf(t, t, s);
        t = wb.y - xb.y; s = fmaf(t, t, s);
        t = wb.z - xb.z; s = fmaf(t, t, s);
        t = wb.w - xb.w; s = fmaf(t, t, s);
        d[r] = s;
    }

    #pragma unroll
    for (int off = 32; off > 0; off >>= 1) {
        #pragma unroll
        for (int r = 0; r < FB_RPW; ++r)
            d[r] += __shfl_xor(d[r], off, 64);
    }

    unsigned long long best = ~0ull;
    #pragma unroll
    for (int r = 0; r < FB_RPW; ++r) {
        unsigned long long key =
            (((unsigned long long)__float_as_uint(d[r])) << 32) |
            (unsigned long long)(unsigned)(row0 + r);
        best = (key < best) ? key : best;
    }

    __shared__ unsigned long long sbest[FB_WPB];
    if (lane == 0) sbest[wave] = best;
    __syncthreads();
    if (threadIdx.x == 0) {
        unsigned long long b = sbest[0];
        #pragma unroll
        for (int i = 1; i < FB_WPB; ++i) b = (sbest[i] < b) ? sbest[i] : b;
        slots[blockIdx.x] = b;
    }
}

__global__ __launch_bounds__(256) void som_update_kernel(
    const float* __restrict__ x,
    const float* __restrict__ w,
    const int* __restrict__ it_ptr,
    const unsigned long long* __restrict__ slots,
    float* __restrict__ out)
{
    const int lane  = threadIdx.x & 63;
    const int wave  = threadIdx.x >> 6;

    unsigned long long b = ~0ull;
    for (int i = threadIdx.x; i < FB_BLOCKS; i += 256) {
        unsigned long long v = slots[i];
        b = (v < b) ? v : b;
    }
    #pragma unroll
    for (int off = 32; off > 0; off >>= 1) {
        unsigned long long o = __shfl_xor(b, off, 64);
        b = (o < b) ? o : b;
    }
    __shared__ unsigned long long sbest[FB_WPB];
    if (lane == 0) sbest[wave] = b;
    __syncthreads();
    unsigned long long g = sbest[0];
    #pragma unroll
    for (int i = 1; i < FB_WPB; ++i) g = (sbest[i] < g) ? sbest[i] : g;

    const unsigned bmu = (unsigned)(g & 0xFFFFFFFFull);
    const float bi = (float)(bmu >> 8);
    const float bj = (float)(bmu & 255u);

    const double itd      = (double)(*it_ptr);
    const double lr       = 1.0 - itd / 1000.0;
    const float  alpha_op = (float)(0.3 * lr);
    const double sigma_op = 128.0 * lr;
    const float  inv_s2   = (float)(1.0 / (sigma_op * sigma_op));

    const float4* x4 = reinterpret_cast<const float4*>(x);
    const float4 xa = x4[lane];
    const float4 xb = x4[lane + 64];

    float* winner      = out;
    float* new_weights = out + DIMD;

    const int gwave = blockIdx.x * FB_WPB + wave;
    const int row0  = gwave * FB_RPW;

    #pragma unroll
    for (int r = 0; r < FB_RPW; ++r) {
        const int row = row0 + r;
        const float di = (float)(row >> 8) - bi;
        const float dj = (float)(row & 255) - bj;
        const float coef = alpha_op * __expf(-(di * di + dj * dj) * inv_s2);

        const float4* w4 =
            reinterpret_cast<const float4*>(w + (size_t)row * DIMD);
        const float4 wa = w4[lane];
        const float4 wb = w4[lane + 64];

        vfloat4 oa, ob;
        oa.x = fmaf(coef, xa.x - wa.x, wa.x);
        oa.y = fmaf(coef, xa.y - wa.y, wa.y);
        oa.z = fmaf(coef, xa.z - wa.z, wa.z);
        oa.w = fmaf(coef, xa.w - wa.w, wa.w);
        ob.x = fmaf(coef, xb.x - wb.x, wb.x);
        ob.y = fmaf(coef, xb.y - wb.y, wb.y);
        ob.z = fmaf(coef, xb.z - wb.z, wb.z);
        ob.w = fmaf(coef, xb.w - wb.w, wb.w);

        vfloat4* o4 = reinterpret_cast<vfloat4*>(new_weights + (size_t)row * DIMD);
        __builtin_nontemporal_store(oa, o4 + lane);
        __builtin_nontemporal_store(ob, o4 + lane + 64);

        if (row == (int)bmu) {
            float4* wn = reinterpret_cast<float4*>(winner);
            wn[lane]      = wa;
            wn[lane + 64] = wb;
        }
    }
}

extern "C" void kernel_launch(void* const* d_in, const int* in_sizes, int n_in,
                              void* d_out, int out_size, void* d_ws, size_t ws_size,
                              hipStream_t stream) {
    const float* x       = (const float*)d_in[0];
    const float* weights = (const float*)d_in[1];
    const int*   it_ptr  = (const int*)d_in[3];
    float* out = (float*)d_out;

    unsigned long long* slots  = (unsigned long long*)d_ws;
    int*                bar    = (int*)((char*)d_ws + 4096);
    unsigned long long* slots2 = (unsigned long long*)((char*)d_ws + 8192);

    // ONE fill covers slots (0xFF.. = +inf keys) AND bar (cnt=-1, flag=-1).
    hipMemsetAsync(d_ws, 0xFF, 4096 + 2 * sizeof(int), stream);

    void* args[] = { (void*)&x, (void*)&weights, (void*)&it_ptr,
                     (void*)&slots, (void*)&bar, (void*)&out };
    hipError_t err = hipLaunchCooperativeKernel((const void*)som_fused,
                                                dim3(GRID), dim3(BLOCK),
                                                args, 0, stream);
    if (err != hipSuccess) {
        (void)hipGetLastError();
        som_argmin_kernel<<<FB_BLOCKS, 256, 0, stream>>>(x, weights, slots2);
        som_update_kernel<<<FB_BLOCKS, 256, 0, stream>>>(x, weights, it_ptr,
                                                         slots2, out);
    }
}

// Round 9
// 69.390 us; speedup vs baseline: 2.7930x; 2.7930x over previous
//
#include <hip/hip_runtime.h>
#include <stdint.h>

#define DIMD 512
#define ROWS 65536

// ---- fused cooperative geometry ----
#define GRID  512
#define BLOCK 512               // 8 waves/block; needs 2 blocks/CU co-resident
#define WPB   8
#define RPW   16                // rows/wave: 6 named-reg + 4 LDS + 6 L3-reread
#define LDS_ROWS 4              // 32 rows/block * 2 KiB = 64 KiB LDS

// ---- fallback (proven R3) geometry ----
#define FB_BLOCKS 2048
#define FB_WPB    4
#define FB_RPW    8

typedef float vfloat4 __attribute__((ext_vector_type(4)));

// distance accumulate + wave-reduce + running min-key
__device__ __forceinline__ void dist_min(const float4 wa, const float4 wb,
                                         const float4 xa, const float4 xb,
                                         int row, unsigned long long& best)
{
    float s = 0.0f, t;
    t = wa.x - xa.x; s = fmaf(t, t, s);
    t = wa.y - xa.y; s = fmaf(t, t, s);
    t = wa.z - xa.z; s = fmaf(t, t, s);
    t = wa.w - xa.w; s = fmaf(t, t, s);
    t = wb.x - xb.x; s = fmaf(t, t, s);
    t = wb.y - xb.y; s = fmaf(t, t, s);
    t = wb.z - xb.z; s = fmaf(t, t, s);
    t = wb.w - xb.w; s = fmaf(t, t, s);
    #pragma unroll
    for (int off = 32; off > 0; off >>= 1)
        s += __shfl_xor(s, off, 64);
    const unsigned long long key =
        (((unsigned long long)__float_as_uint(s)) << 32) |
        (unsigned long long)(unsigned)row;
    best = (key < best) ? key : best;
}

// fused update + winner extraction for one row
__device__ __forceinline__ void update_row(const float4 wa, const float4 wb,
                                           const float4 xa, const float4 xb,
                                           int row, unsigned bmu,
                                           float bi, float bj,
                                           float alpha_op, float inv_s2,
                                           float* __restrict__ winner,
                                           float* __restrict__ new_weights,
                                           int lane)
{
    const float di = (float)(row >> 8) - bi;
    const float dj = (float)(row & 255) - bj;
    const float coef = alpha_op * __expf(-(di * di + dj * dj) * inv_s2);

    vfloat4 oa, ob;
    oa.x = fmaf(coef, xa.x - wa.x, wa.x);
    oa.y = fmaf(coef, xa.y - wa.y, wa.y);
    oa.z = fmaf(coef, xa.z - wa.z, wa.z);
    oa.w = fmaf(coef, xa.w - wa.w, wa.w);
    ob.x = fmaf(coef, xb.x - wb.x, wb.x);
    ob.y = fmaf(coef, xb.y - wb.y, wb.y);
    ob.z = fmaf(coef, xb.z - wb.z, wb.z);
    ob.w = fmaf(coef, xb.w - wb.w, wb.w);

    vfloat4* o4 = reinterpret_cast<vfloat4*>(new_weights + (size_t)row * DIMD);
    __builtin_nontemporal_store(oa, o4 + lane);
    __builtin_nontemporal_store(ob, o4 + lane + 64);

    if (row == (int)bmu) {
        float4* wn = reinterpret_cast<float4*>(winner);
        wn[lane]      = wa;   // OLD weights row
        wn[lane + 64] = wb;
    }
}

// ===========================================================================
// FUSED PATH (cooperative). Phase 1 streams each weight row once from HBM;
// rows 0-5 in named registers, 6-9 in LDS, 10-15 re-read from cache in
// phase 2. NO __launch_bounds__: R5-R7 showed a forced 64-VGPR cap (wholesale
// spill, 57 MB scratch). Unconstrained, the kernel needs ~90 VGPR -> natural
// occupancy 2 blocks/CU; the HOST verifies that via the occupancy query
// before attempting the cooperative launch (spin barrier never runs without
// verified co-residency).
// ===========================================================================
__global__ void som_fused(
    const float* __restrict__ x,
    const float* __restrict__ w,
    const int* __restrict__ it_ptr,
    unsigned long long* __restrict__ slots,   // [GRID], 0xFF per call
    int* __restrict__ bar,                    // [2] = {cnt, flag}, 0xFF init
    float* __restrict__ out)
{
    __shared__ float lds[WPB * LDS_ROWS * DIMD];   // 64 KiB

    const int lane = threadIdx.x & 63;
    const int wave = threadIdx.x >> 6;
    const int row0 = (blockIdx.x * WPB + wave) * RPW;

    const float4* x4 = reinterpret_cast<const float4*>(x);
    const float4 xa = x4[lane];
    const float4 xb = x4[lane + 64];

    const float4* wb4 = reinterpret_cast<const float4*>(w);
    unsigned long long best = ~0ull;

    // ---- phase 1: rows 0-5 -> named registers ----
    float4 a0, b0, a1, b1, a2, b2, a3, b3, a4, b4, a5, b5;
    {
        const float4* p;
        p = wb4 + (size_t)(row0 + 0) * (DIMD / 4);
        a0 = p[lane]; b0 = p[lane + 64]; dist_min(a0, b0, xa, xb, row0 + 0, best);
        p = wb4 + (size_t)(row0 + 1) * (DIMD / 4);
        a1 = p[lane]; b1 = p[lane + 64]; dist_min(a1, b1, xa, xb, row0 + 1, best);
        p = wb4 + (size_t)(row0 + 2) * (DIMD / 4);
        a2 = p[lane]; b2 = p[lane + 64]; dist_min(a2, b2, xa, xb, row0 + 2, best);
        p = wb4 + (size_t)(row0 + 3) * (DIMD / 4);
        a3 = p[lane]; b3 = p[lane + 64]; dist_min(a3, b3, xa, xb, row0 + 3, best);
        p = wb4 + (size_t)(row0 + 4) * (DIMD / 4);
        a4 = p[lane]; b4 = p[lane + 64]; dist_min(a4, b4, xa, xb, row0 + 4, best);
        p = wb4 + (size_t)(row0 + 5) * (DIMD / 4);
        a5 = p[lane]; b5 = p[lane + 64]; dist_min(a5, b5, xa, xb, row0 + 5, best);
    }

    // ---- phase 1: rows 6-9 -> LDS ----
    #pragma unroll
    for (int r = 6; r < 6 + LDS_ROWS; ++r) {
        const float4* p = wb4 + (size_t)(row0 + r) * (DIMD / 4);
        const float4 wa = p[lane];
        const float4 wbv = p[lane + 64];
        float4* dst = reinterpret_cast<float4*>(
            lds + (wave * LDS_ROWS + (r - 6)) * DIMD);
        dst[lane]      = wa;
        dst[lane + 64] = wbv;
        dist_min(wa, wbv, xa, xb, row0 + r, best);
    }

    // ---- phase 1: rows 10-15 -> distance only (phase 2 re-reads, cache-hot) ----
    #pragma unroll
    for (int r = 10; r < 16; ++r) {
        const float4* p = wb4 + (size_t)(row0 + r) * (DIMD / 4);
        dist_min(p[lane], p[lane + 64], xa, xb, row0 + r, best);
    }

    if (lane == 0) atomicMin(&slots[blockIdx.x], best);

    // ---- grid barrier: arrive (release) / spin (acquire), -1-based ----
    __syncthreads();
    if (threadIdx.x == 0) {
        __threadfence();
        const int old = __hip_atomic_fetch_add(&bar[0], 1, __ATOMIC_ACQ_REL,
                                               __HIP_MEMORY_SCOPE_AGENT);
        if (old == GRID - 2) {
            __hip_atomic_store(&bar[1], 1, __ATOMIC_RELEASE,
                               __HIP_MEMORY_SCOPE_AGENT);
        } else {
            while (__hip_atomic_load(&bar[1], __ATOMIC_ACQUIRE,
                                     __HIP_MEMORY_SCOPE_AGENT) == -1) {
                __builtin_amdgcn_s_sleep(2);
            }
        }
        __threadfence();
    }
    __syncthreads();

    // ---- every wave reduces the 512 per-block candidates ----
    unsigned long long g = ~0ull;
    #pragma unroll
    for (int k = 0; k < GRID / 64; ++k) {
        const unsigned long long v = slots[k * 64 + lane];
        g = (v < g) ? v : g;
    }
    #pragma unroll
    for (int off = 32; off > 0; off >>= 1) {
        const unsigned long long o = __shfl_xor(g, off, 64);
        g = (o < g) ? o : g;
    }

    const unsigned bmu = (unsigned)(g & 0xFFFFFFFFull);
    const float bi = (float)(bmu >> 8);
    const float bj = (float)(bmu & 255u);

    const double itd      = (double)(*it_ptr);
    const double lr       = 1.0 - itd / 1000.0;
    const float  alpha_op = (float)(0.3 * lr);
    const double sigma_op = 128.0 * lr;            // SIGMA = max(M,N)/2
    const float  inv_s2   = (float)(1.0 / (sigma_op * sigma_op));

    float* winner      = out;
    float* new_weights = out + DIMD;

    // ---- phase 2: re-read rows first (read most recently -> warmest) ----
    #pragma unroll
    for (int r = 10; r < 16; ++r) {
        const float4* p = wb4 + (size_t)(row0 + r) * (DIMD / 4);
        update_row(p[lane], p[lane + 64], xa, xb, row0 + r, bmu,
                   bi, bj, alpha_op, inv_s2, winner, new_weights, lane);
    }

    // ---- phase 2: LDS rows ----
    #pragma unroll
    for (int r = 6; r < 6 + LDS_ROWS; ++r) {
        const float4* src = reinterpret_cast<const float4*>(
            lds + (wave * LDS_ROWS + (r - 6)) * DIMD);
        update_row(src[lane], src[lane + 64], xa, xb, row0 + r, bmu,
                   bi, bj, alpha_op, inv_s2, winner, new_weights, lane);
    }

    // ---- phase 2: named-register rows ----
    update_row(a0, b0, xa, xb, row0 + 0, bmu, bi, bj, alpha_op, inv_s2, winner, new_weights, lane);
    update_row(a1, b1, xa, xb, row0 + 1, bmu, bi, bj, alpha_op, inv_s2, winner, new_weights, lane);
    update_row(a2, b2, xa, xb, row0 + 2, bmu, bi, bj, alpha_op, inv_s2, winner, new_weights, lane);
    update_row(a3, b3, xa, xb, row0 + 3, bmu, bi, bj, alpha_op, inv_s2, winner, new_weights, lane);
    update_row(a4, b4, xa, xb, row0 + 4, bmu, bi, bj, alpha_op, inv_s2, winner, new_weights, lane);
    update_row(a5, b5, xa, xb, row0 + 5, bmu, bi, bj, alpha_op, inv_s2, winner, new_weights, lane);
}

// ===========================================================================
// FALLBACK PATH — byte-identical to the proven R3 two-kernel version.
// ===========================================================================
__global__ __launch_bounds__(256) void som_argmin_kernel(
    const float* __restrict__ x,
    const float* __restrict__ w,
    unsigned long long* __restrict__ slots)
{
    const int lane  = threadIdx.x & 63;
    const int wave  = threadIdx.x >> 6;
    const int gwave = blockIdx.x * FB_WPB + wave;
    const int row0  = gwave * FB_RPW;

    const float4* x4 = reinterpret_cast<const float4*>(x);
    const float4 xa = x4[lane];
    const float4 xb = x4[lane + 64];

    float d[FB_RPW];

    #pragma unroll
    for (int r = 0; r < FB_RPW; ++r) {
        const float4* w4 =
            reinterpret_cast<const float4*>(w + (size_t)(row0 + r) * DIMD);
        const float4 wa = w4[lane];
        const float4 wb = w4[lane + 64];

        float s = 0.0f, t;
        t = wa.x - xa.x; s = fmaf(t, t, s);
        t = wa.y - xa.y; s = fmaf(t, t, s);
        t = wa.z - xa.z; s = fmaf(t, t, s);
        t = wa.w - xa.w; s = fmaf(t, t, s);
        t = wb.x - xb.x; s = fmaf(t, t, s);
        t = wb.y - xb.y; s = fmaf(t, t, s);
        t = wb.z - xb.z; s = fmaf(t, t, s);
        t = wb.w - xb.w; s = fmaf(t, t, s);
        d[r] = s;
    }

    #pragma unroll
    for (int off = 32; off > 0; off >>= 1) {
        #pragma unroll
        for (int r = 0; r < FB_RPW; ++r)
            d[r] += __shfl_xor(d[r], off, 64);
    }

    unsigned long long best = ~0ull;
    #pragma unroll
    for (int r = 0; r < FB_RPW; ++r) {
        unsigned long long key =
            (((unsigned long long)__float_as_uint(d[r])) << 32) |
            (unsigned long long)(unsigned)(row0 + r);
        best = (key < best) ? key : best;
    }

    __shared__ unsigned long long sbest[FB_WPB];
    if (lane == 0) sbest[wave] = best;
    __syncthreads();
    if (threadIdx.x == 0) {
        unsigned long long b = sbest[0];
        #pragma unroll
        for (int i = 1; i < FB_WPB; ++i) b = (sbest[i] < b) ? sbest[i] : b;
        slots[blockIdx.x] = b;
    }
}

__global__ __launch_bounds__(256) void som_update_kernel(
    const float* __restrict__ x,
    const float* __restrict__ w,
    const int* __restrict__ it_ptr,
    const unsigned long long* __restrict__ slots,
    float* __restrict__ out)
{
    const int lane  = threadIdx.x & 63;
    const int wave  = threadIdx.x >> 6;

    unsigned long long b = ~0ull;
    for (int i = threadIdx.x; i < FB_BLOCKS; i += 256) {
        unsigned long long v = slots[i];
        b = (v < b) ? v : b;
    }
    #pragma unroll
    for (int off = 32; off > 0; off >>= 1) {
        unsigned long long o = __shfl_xor(b, off, 64);
        b = (o < b) ? o : b;
    }
    __shared__ unsigned long long sbest[FB_WPB];
    if (lane == 0) sbest[wave] = b;
    __syncthreads();
    unsigned long long g = sbest[0];
    #pragma unroll
    for (int i = 1; i < FB_WPB; ++i) g = (sbest[i] < g) ? sbest[i] : g;

    const unsigned bmu = (unsigned)(g & 0xFFFFFFFFull);
    const float bi = (float)(bmu >> 8);
    const float bj = (float)(bmu & 255u);

    const double itd      = (double)(*it_ptr);
    const double lr       = 1.0 - itd / 1000.0;
    const float  alpha_op = (float)(0.3 * lr);
    const double sigma_op = 128.0 * lr;
    const float  inv_s2   = (float)(1.0 / (sigma_op * sigma_op));

    const float4* x4 = reinterpret_cast<const float4*>(x);
    const float4 xa = x4[lane];
    const float4 xb = x4[lane + 64];

    float* winner      = out;
    float* new_weights = out + DIMD;

    const int gwave = blockIdx.x * FB_WPB + wave;
    const int row0  = gwave * FB_RPW;

    #pragma unroll
    for (int r = 0; r < FB_RPW; ++r) {
        const int row = row0 + r;
        const float di = (float)(row >> 8) - bi;
        const float dj = (float)(row & 255) - bj;
        const float coef = alpha_op * __expf(-(di * di + dj * dj) * inv_s2);

        const float4* w4 =
            reinterpret_cast<const float4*>(w + (size_t)row * DIMD);
        const float4 wa = w4[lane];
        const float4 wb = w4[lane + 64];

        vfloat4 oa, ob;
        oa.x = fmaf(coef, xa.x - wa.x, wa.x);
        oa.y = fmaf(coef, xa.y - wa.y, wa.y);
        oa.z = fmaf(coef, xa.z - wa.z, wa.z);
        oa.w = fmaf(coef, xa.w - wa.w, wa.w);
        ob.x = fmaf(coef, xb.x - wb.x, wb.x);
        ob.y = fmaf(coef, xb.y - wb.y, wb.y);
        ob.z = fmaf(coef, xb.z - wb.z, wb.z);
        ob.w = fmaf(coef, xb.w - wb.w, wb.w);

        vfloat4* o4 = reinterpret_cast<vfloat4*>(new_weights + (size_t)row * DIMD);
        __builtin_nontemporal_store(oa, o4 + lane);
        __builtin_nontemporal_store(ob, o4 + lane + 64);

        if (row == (int)bmu) {
            float4* wn = reinterpret_cast<float4*>(winner);
            wn[lane]      = wa;
            wn[lane + 64] = wb;
        }
    }
}

extern "C" void kernel_launch(void* const* d_in, const int* in_sizes, int n_in,
                              void* d_out, int out_size, void* d_ws, size_t ws_size,
                              hipStream_t stream) {
    const float* x       = (const float*)d_in[0];
    const float* weights = (const float*)d_in[1];
    const int*   it_ptr  = (const int*)d_in[3];
    float* out = (float*)d_out;

    unsigned long long* slots  = (unsigned long long*)d_ws;
    int*                bar    = (int*)((char*)d_ws + 4096);
    unsigned long long* slots2 = (unsigned long long*)((char*)d_ws + 8192);

    // Host-side co-residency guard (pure query, graph-capture-safe,
    // deterministic). Only trust the spin barrier if the runtime itself says
    // >= 2 blocks/CU fit for this kernel's actual VGPR/LDS usage.
    int occ = 0;
    hipError_t qerr = hipOccupancyMaxActiveBlocksPerMultiprocessor(
        &occ, som_fused, BLOCK, 0);
    bool try_fused = (qerr == hipSuccess) && (occ >= 2);

    if (try_fused) {
        // ONE fill covers slots (0xFF.. = +inf keys) AND bar (cnt=-1, flag=-1).
        hipMemsetAsync(d_ws, 0xFF, 4096 + 2 * sizeof(int), stream);
        void* args[] = { (void*)&x, (void*)&weights, (void*)&it_ptr,
                         (void*)&slots, (void*)&bar, (void*)&out };
        hipError_t err = hipLaunchCooperativeKernel((const void*)som_fused,
                                                    dim3(GRID), dim3(BLOCK),
                                                    args, 0, stream);
        if (err == hipSuccess) return;
        (void)hipGetLastError();   // clear sticky error, fall through
    }

    som_argmin_kernel<<<FB_BLOCKS, 256, 0, stream>>>(x, weights, slots2);
    som_update_kernel<<<FB_BLOCKS, 256, 0, stream>>>(x, weights, it_ptr,
                                                     slots2, out);
}

// Round 10
// 69.312 us; speedup vs baseline: 2.7961x; 1.0011x over previous
//
#include <hip/hip_runtime.h>
#include <stdint.h>

#define DIMD 512
#define ROWS 65536

#define K_BLOCKS 2048
#define WPB      4              // waves per block
#define RPW      8              // rows per wave: 2048*4*8 = 65536

typedef float vfloat4 __attribute__((ext_vector_type(4)));

// ---------------------------------------------------------------------------
// Kernel 1: BMU search. One wave per 8-row strip, fully unrolled: 8
// independent distance accumulations, then 8 ILP-overlapped butterfly
// reductions. Lane reads float4 chunks (lane) and (lane+64) -> each load
// instruction covers a dense contiguous 1024 B. Key = (dist_bits<<32)|row:
// min-key == min distance with first-index tie-break (distances >= 0, float
// bits order-preserving). Per-block best plain-stored (no init, no atomics).
// Weight reads are NORMAL loads -> they fill Infinity Cache for kernel 2.
// ---------------------------------------------------------------------------
__global__ __launch_bounds__(256) void som_argmin_kernel(
    const float* __restrict__ x,
    const float* __restrict__ w,
    unsigned long long* __restrict__ slots)
{
    const int lane  = threadIdx.x & 63;
    const int wave  = threadIdx.x >> 6;
    const int gwave = blockIdx.x * WPB + wave;
    const int row0  = gwave * RPW;

    const float4* x4 = reinterpret_cast<const float4*>(x);
    const float4 xa = x4[lane];
    const float4 xb = x4[lane + 64];

    float d[RPW];

    #pragma unroll
    for (int r = 0; r < RPW; ++r) {
        const float4* w4 =
            reinterpret_cast<const float4*>(w + (size_t)(row0 + r) * DIMD);
        const float4 wa = w4[lane];
        const float4 wb = w4[lane + 64];

        float s = 0.0f, t;
        t = wa.x - xa.x; s = fmaf(t, t, s);
        t = wa.y - xa.y; s = fmaf(t, t, s);
        t = wa.z - xa.z; s = fmaf(t, t, s);
        t = wa.w - xa.w; s = fmaf(t, t, s);
        t = wb.x - xb.x; s = fmaf(t, t, s);
        t = wb.y - xb.y; s = fmaf(t, t, s);
        t = wb.z - xb.z; s = fmaf(t, t, s);
        t = wb.w - xb.w; s = fmaf(t, t, s);
        d[r] = s;
    }

    // 8 independent butterfly reductions (ILP-pipelined on the DS pipe).
    #pragma unroll
    for (int off = 32; off > 0; off >>= 1) {
        #pragma unroll
        for (int r = 0; r < RPW; ++r)
            d[r] += __shfl_xor(d[r], off, 64);
    }

    unsigned long long best = ~0ull;
    #pragma unroll
    for (int r = 0; r < RPW; ++r) {
        unsigned long long key =
            (((unsigned long long)__float_as_uint(d[r])) << 32) |
            (unsigned long long)(unsigned)(row0 + r);
        best = (key < best) ? key : best;
    }

    __shared__ unsigned long long sbest[WPB];
    if (lane == 0) sbest[wave] = best;
    __syncthreads();
    if (threadIdx.x == 0) {
        unsigned long long b = sbest[0];
        #pragma unroll
        for (int i = 1; i < WPB; ++i) b = (sbest[i] < b) ? sbest[i] : b;
        slots[blockIdx.x] = b;
    }
}

// ---------------------------------------------------------------------------
// Kernel 2: slot-reduce (2048 x 8 B, L2-hot) -> bmu broadcast -> streaming
// fused update with nontemporal stores. Rows processed in REVERSE block
// order: kernel 1 streamed rows 0->65535 through Infinity Cache, so the
// highest rows are freshest -- K2's earliest blocks re-read those first
// (IC-retention experiment; neutral if IC doesn't retain).
// Winner = OLD weights[bmu], written by the wave that owns that row.
// ---------------------------------------------------------------------------
__global__ __launch_bounds__(256) void som_update_kernel(
    const float* __restrict__ x,
    const float* __restrict__ w,
    const int* __restrict__ it_ptr,
    const unsigned long long* __restrict__ slots,
    float* __restrict__ out)
{
    const int lane = threadIdx.x & 63;
    const int wave = threadIdx.x >> 6;

    // ---- reduce the 2048 per-block candidates, broadcast bmu ----
    unsigned long long b = ~0ull;
    for (int i = threadIdx.x; i < K_BLOCKS; i += 256) {
        unsigned long long v = slots[i];
        b = (v < b) ? v : b;
    }
    #pragma unroll
    for (int off = 32; off > 0; off >>= 1) {
        unsigned long long o = __shfl_xor(b, off, 64);
        b = (o < b) ? o : b;
    }
    __shared__ unsigned long long sbest[WPB];
    if (lane == 0) sbest[wave] = b;
    __syncthreads();
    unsigned long long g = sbest[0];
    #pragma unroll
    for (int i = 1; i < WPB; ++i) g = (sbest[i] < g) ? sbest[i] : g;

    const unsigned bmu = (unsigned)(g & 0xFFFFFFFFull);
    const float bi = (float)(bmu >> 8);
    const float bj = (float)(bmu & 255u);

    // scalar decay math in double, matching Python semantics
    const double itd      = (double)(*it_ptr);
    const double lr       = 1.0 - itd / 1000.0;
    const float  alpha_op = (float)(0.3 * lr);
    const double sigma_op = 128.0 * lr;           // SIGMA = max(M,N)/2
    const float  inv_s2   = (float)(1.0 / (sigma_op * sigma_op));

    const float4* x4 = reinterpret_cast<const float4*>(x);
    const float4 xa = x4[lane];
    const float4 xb = x4[lane + 64];

    float* winner      = out;          // first 512 floats
    float* new_weights = out + DIMD;   // then 65536 x 512

    // reversed block order (IC-freshness)
    const int rblk  = (K_BLOCKS - 1) - blockIdx.x;
    const int gwave = rblk * WPB + wave;
    const int row0  = gwave * RPW;

    #pragma unroll
    for (int r = 0; r < RPW; ++r) {
        const int row = row0 + r;
        const float di = (float)(row >> 8) - bi;
        const float dj = (float)(row & 255) - bj;
        const float coef = alpha_op * __expf(-(di * di + dj * dj) * inv_s2);

        const float4* w4 =
            reinterpret_cast<const float4*>(w + (size_t)row * DIMD);
        const float4 wa = w4[lane];
        const float4 wb = w4[lane + 64];

        vfloat4 oa, ob;
        oa.x = fmaf(coef, xa.x - wa.x, wa.x);
        oa.y = fmaf(coef, xa.y - wa.y, wa.y);
        oa.z = fmaf(coef, xa.z - wa.z, wa.z);
        oa.w = fmaf(coef, xa.w - wa.w, wa.w);
        ob.x = fmaf(coef, xb.x - wb.x, wb.x);
        ob.y = fmaf(coef, xb.y - wb.y, wb.y);
        ob.z = fmaf(coef, xb.z - wb.z, wb.z);
        ob.w = fmaf(coef, xb.w - wb.w, wb.w);

        vfloat4* o4 = reinterpret_cast<vfloat4*>(new_weights + (size_t)row * DIMD);
        __builtin_nontemporal_store(oa, o4 + lane);
        __builtin_nontemporal_store(ob, o4 + lane + 64);

        if (row == (int)bmu) {
            float4* wn = reinterpret_cast<float4*>(winner);
            wn[lane]      = wa;   // OLD weights row
            wn[lane + 64] = wb;
        }
    }
}

extern "C" void kernel_launch(void* const* d_in, const int* in_sizes, int n_in,
                              void* d_out, int out_size, void* d_ws, size_t ws_size,
                              hipStream_t stream) {
    const float* x       = (const float*)d_in[0];
    const float* weights = (const float*)d_in[1];
    // d_in[2] = y (unused by the math)
    const int*   it_ptr  = (const int*)d_in[3];

    float* out = (float*)d_out;
    unsigned long long* slots = (unsigned long long*)d_ws;  // 2048 * 8 B

    som_argmin_kernel<<<K_BLOCKS, 256, 0, stream>>>(x, weights, slots);
    som_update_kernel<<<K_BLOCKS, 256, 0, stream>>>(x, weights, it_ptr, slots, out);
}